// Round 6
// baseline (377.344 us; speedup 1.0000x reference)
//
#include <hip/hip_runtime.h>
#include <math.h>

// SoftGate: gate-MLP (split-bf16 MFMA, pipelined) -> threshold -> compaction.
// R11: k2b fused into k1 via last-block-per-row (threadfence reduction idiom).
#define NB 8
#define NS 4096
#define ND 1024      // K (feature dim)
#define NDH 512      // N (hidden dim)
#define NTOK (NB*NS) // M = 32768
#define THRESH 0.1f
#define EPSV 1e-5f

using short8   = __attribute__((ext_vector_type(8)))  short;
using floatx16 = __attribute__((ext_vector_type(16))) float;
using floatv4  = __attribute__((ext_vector_type(4)))  float;  // native vec for nontemporal

__device__ __forceinline__ unsigned short f32_to_bf16_rne(float f) {
  union { float f; unsigned u; } v; v.f = f;
  unsigned r = v.u + 0x7fffu + ((v.u >> 16) & 1u);
  return (unsigned short)(r >> 16);
}
__device__ __forceinline__ float bf16_to_f32(unsigned short h) {
  union { unsigned u; float f; } v; v.u = ((unsigned)h) << 16;
  return v.f;
}

// ---------------------------------------------------------------------------
// K0: repack W1 into MFMA-B-fragment order, bf16 hi/lo by 1 KB chunk:
//   chunk(n32,k16): lane l holds n=n32*32+(l&31), k=k16*16+(l>>5)*8+j.
// Also zero-inits done_cnt for k1's last-block-per-row handoff.
// ---------------------------------------------------------------------------
__global__ __launch_bounds__(256)
void k0_prep(const float* __restrict__ W1, unsigned short* __restrict__ Wf,
             int* __restrict__ done_cnt) {
  __shared__ float sw[16][513];
  const int t = threadIdx.x;
  const int k16 = blockIdx.x;                // 0..63
  if (k16 == 0 && t < NB) done_cnt[t] = 0;
#pragma unroll
  for (int i = 0; i < 8; ++i) {
    int flat = i * 256 + t;
    int r = flat >> 7, c4 = (flat & 127) << 2;
    *(float4*)&sw[r][c4] = *(const float4*)(W1 + (size_t)(k16 * 16 + r) * NDH + c4);
  }
  __syncthreads();
#pragma unroll
  for (int q = 0; q < 4; ++q) {
    int ss = q * 256 + t;
    int n32 = ss >> 6, lane = ss & 63;
    int n = n32 * 32 + (lane & 31);
    int kb = (lane >> 5) * 8;
    unsigned hi2[4], lo2[4];
#pragma unroll
    for (int j = 0; j < 4; ++j) {
      float w0 = sw[kb + 2 * j][n], w1 = sw[kb + 2 * j + 1][n];
      unsigned short h0 = f32_to_bf16_rne(w0), h1 = f32_to_bf16_rne(w1);
      unsigned short l0 = f32_to_bf16_rne(w0 - bf16_to_f32(h0));
      unsigned short l1 = f32_to_bf16_rne(w1 - bf16_to_f32(h1));
      hi2[j] = (unsigned)h0 | ((unsigned)h1 << 16);
      lo2[j] = (unsigned)l0 | ((unsigned)l1 << 16);
    }
    size_t cb = ((size_t)(n32 * 64 + k16) * 2) * 512 + (size_t)lane * 8;
    *(uint4*)(Wf + cb)       = make_uint4(hi2[0], hi2[1], hi2[2], hi2[3]);
    *(uint4*)(Wf + cb + 512) = make_uint4(lo2[0], lo2[1], lo2[2], lo2[3]);
  }
}

// ---------------------------------------------------------------------------
// K1: fused gate MLP. 3-term split-bf16 MFMA (hi·hi + lo·hi + hi·lo), fp32 acc.
// GEMM core identical to R9 (BK=64, cooperative LDS staging, term-outer issue,
// reg x-prefetch; bit-identical accumulation). Tail: squash+pad-zero+ysq store,
// then last-block-per-row handoff (release fence -> barrier -> tid0 atomicAdd;
// block with prev==63 acquires and runs the row's full compaction: exact row
// max from ysq (== old atomicMax value since all y>=0), adjust, threshold,
// stable shfl-scan, compaction map, vpad, new_len). Compaction overlaps the
// remaining GEMM blocks -> the k2b dispatch disappears.
// Tripwire: WRITE_SIZE ~5-6 MB (no scratch spill), VGPR_Count 128.
// ---------------------------------------------------------------------------
__global__ __launch_bounds__(256, 2)
void k1_gemm(const float* __restrict__ x, const unsigned short* __restrict__ Wf,
             const float* __restrict__ b1, const float* __restrict__ W2,
             const int* __restrict__ pad, const float* __restrict__ b2,
             float* __restrict__ ysq, int* __restrict__ done_cnt,
             float* __restrict__ gval, int* __restrict__ src_of_dest,
             int* __restrict__ new_len, float* __restrict__ vpad) {
  __shared__ __align__(16) unsigned short sx[2][2][64 * 72];  // [buf][hi/lo][m*72+k]
  __shared__ float red[4][64];
  __shared__ float smax[4];
  __shared__ int ssum[4];
  __shared__ int sflag;

  const int tid = threadIdx.x;
  const int wave = tid >> 6, lane = tid & 63;
  const int l31 = lane & 31, h5 = lane >> 5;
  const int tok0 = blockIdx.x * 64;

  floatx16 acc[2][4];
#pragma unroll
  for (int mt = 0; mt < 2; ++mt)
#pragma unroll
    for (int nt = 0; nt < 4; ++nt)
#pragma unroll
      for (int r = 0; r < 16; ++r) acc[mt][nt][r] = 0.f;

  const int sm = tid >> 2;            // staging row 0..63 (4 threads/row)
  const int sk = (tid & 3) * 16;      // staging k-offset {0,16,32,48}
  const float* xrow = x + (size_t)(tok0 + sm) * ND + sk;

  const unsigned short* wb[4];
#pragma unroll
  for (int nt = 0; nt < 4; ++nt)
    wb[nt] = Wf + (((size_t)(wave * 4 + nt) * 64) * 2) * 512 + (size_t)lane * 8;

  // convert+store 16 staged floats (4x float4) into LDS buffer bf
  auto stage_cvt = [&](int bf, const float4& a0, const float4& a1,
                       const float4& a2, const float4& a3) {
    float v16[16] = {a0.x, a0.y, a0.z, a0.w, a1.x, a1.y, a1.z, a1.w,
                     a2.x, a2.y, a2.z, a2.w, a3.x, a3.y, a3.z, a3.w};
    unsigned hp[8], lp[8];
#pragma unroll
    for (int j = 0; j < 8; ++j) {
      unsigned short h0 = f32_to_bf16_rne(v16[2 * j]);
      unsigned short h1 = f32_to_bf16_rne(v16[2 * j + 1]);
      unsigned short l0 = f32_to_bf16_rne(v16[2 * j] - bf16_to_f32(h0));
      unsigned short l1 = f32_to_bf16_rne(v16[2 * j + 1] - bf16_to_f32(h1));
      hp[j] = (unsigned)h0 | ((unsigned)h1 << 16);
      lp[j] = (unsigned)l0 | ((unsigned)l1 << 16);
    }
    *(uint4*)&sx[bf][0][sm * 72 + sk]     = make_uint4(hp[0], hp[1], hp[2], hp[3]);
    *(uint4*)&sx[bf][0][sm * 72 + sk + 8] = make_uint4(hp[4], hp[5], hp[6], hp[7]);
    *(uint4*)&sx[bf][1][sm * 72 + sk]     = make_uint4(lp[0], lp[1], lp[2], lp[3]);
    *(uint4*)&sx[bf][1][sm * 72 + sk + 8] = make_uint4(lp[4], lp[5], lp[6], lp[7]);
  };

  // prologue: stage x for it=0 into LDS buf 0
  {
    float4 a0 = *(const float4*)xrow;
    float4 a1 = *(const float4*)(xrow + 4);
    float4 a2 = *(const float4*)(xrow + 8);
    float4 a3 = *(const float4*)(xrow + 12);
    stage_cvt(0, a0, a1, a2, a3);
  }

  for (int it = 0; it < 16; ++it) {
    const int p = it & 1;
    __syncthreads();                  // LDS[p] ready; prev-iter prefetch drained
    // x prefetch for NEXT iter: issued first, consumed after the MFMA phase
    float4 pa0, pa1, pa2, pa3;
    if (it < 15) {
      const float* xp = xrow + (it + 1) * 64;
      pa0 = *(const float4*)xp;
      pa1 = *(const float4*)(xp + 4);
      pa2 = *(const float4*)(xp + 8);
      pa3 = *(const float4*)(xp + 12);
    }
    // 4 k16-subphases per barrier phase; B frags loaded per-k16 (progressive
    // vmcnt: k16+1's loads issue during k16's MFMAs).
#pragma unroll
    for (int kh = 0; kh < 4; ++kh) {
      short8 bh[4], bl[4];
#pragma unroll
      for (int nt = 0; nt < 4; ++nt) {
        const unsigned short* q = wb[nt] + ((size_t)(4 * it + kh) * 2) * 512;
        bh[nt] = *(const short8*)(q);
        bl[nt] = *(const short8*)(q + 512);
      }
      // A fragments: lane holds x[tok=mt*32+l31][k = kh*16 + h5*8 + j]
      short8 ah[2], al[2];
#pragma unroll
      for (int mt = 0; mt < 2; ++mt) {
        ah[mt] = *(const short8*)&sx[p][0][(mt * 32 + l31) * 72 + kh * 16 + h5 * 8];
        al[mt] = *(const short8*)&sx[p][1][(mt * 32 + l31) * 72 + kh * 16 + h5 * 8];
      }
      // term-outer MFMA issue: 8 independent accs between same-acc reuse;
      // per-acc order per k16 (hh,lh,hl) identical to R5/R9.
#pragma unroll
      for (int nt = 0; nt < 4; ++nt)
#pragma unroll
        for (int mt = 0; mt < 2; ++mt)
          acc[mt][nt] = __builtin_amdgcn_mfma_f32_32x32x16_bf16(ah[mt], bh[nt], acc[mt][nt], 0, 0, 0);
#pragma unroll
      for (int nt = 0; nt < 4; ++nt)
#pragma unroll
        for (int mt = 0; mt < 2; ++mt)
          acc[mt][nt] = __builtin_amdgcn_mfma_f32_32x32x16_bf16(al[mt], bh[nt], acc[mt][nt], 0, 0, 0);
#pragma unroll
      for (int nt = 0; nt < 4; ++nt)
#pragma unroll
        for (int mt = 0; mt < 2; ++mt)
          acc[mt][nt] = __builtin_amdgcn_mfma_f32_32x32x16_bf16(ah[mt], bl[nt], acc[mt][nt], 0, 0, 0);
    }
    // convert prefetched x -> other LDS buffer (ready for next barrier)
    if (it < 15) stage_cvt(p ^ 1, pa0, pa1, pa2, pa3);
  }

  // epilogue: relu(h+b1)*W2, shfl-reduce 32 col-lanes, LDS combine.
  // C/D layout (m74/m101): col=lane&31, row=(r&3)+8*(r>>2)+4*(lane>>5)
  float b1v[4], w2v[4];
#pragma unroll
  for (int nt = 0; nt < 4; ++nt) {
    const int n = wave * 128 + nt * 32 + l31;
    b1v[nt] = b1[n];
    w2v[nt] = W2[n];
  }
#pragma unroll
  for (int mt = 0; mt < 2; ++mt) {
    float pr[16];
#pragma unroll
    for (int r = 0; r < 16; ++r) pr[r] = 0.f;
#pragma unroll
    for (int nt = 0; nt < 4; ++nt)
#pragma unroll
      for (int r = 0; r < 16; ++r)
        pr[r] += fmaxf(acc[mt][nt][r] + b1v[nt], 0.f) * w2v[nt];
#pragma unroll
    for (int m = 1; m <= 16; m <<= 1)
#pragma unroll
      for (int r = 0; r < 16; ++r) pr[r] += __shfl_xor(pr[r], m, 64);
    if (l31 == 0) {
#pragma unroll
      for (int r = 0; r < 16; ++r) {
        int row = (r & 3) + 8 * (r >> 2) + 4 * h5;
        red[wave][mt * 32 + row] = pr[r];
      }
    }
  }
  __syncthreads();
  // squash, pad-zero, store ysq
  if (tid < 64) {
    float s = red[0][tid] + red[1][tid] + red[2][tid] + red[3][tid];
    const int t = tok0 + tid;
    float yl = s + b2[0];
    float y = (1.f + tanhf(10.f * yl)) * 0.5f;
    if (pad[t]) y = 0.f;
    ysq[t] = y;
  }
  // --- last-block-per-row handoff (threadfence reduction idiom) ---
  __threadfence();                 // release: ysq stores visible device-wide
  __syncthreads();                 // all lanes' stores+fences precede the count
  const int brow = tok0 >> 12;     // 64 blocks per row
  if (tid == 0) {
    int prev = atomicAdd(&done_cnt[brow], 1);
    sflag = (prev == 63) ? 1 : 0;
  }
  __syncthreads();
  if (sflag) {
    __threadfence();               // acquire: other blocks' ysq now readable
    const int base = brow * NS, s0 = tid * 16;
    const int wv = wave;
    float yv[16];
#pragma unroll
    for (int i = 0; i < 16; ++i) yv[i] = ysq[base + s0 + i];
    // exact row max (all y >= 0; fmax reduce == old uint atomicMax value)
    float m = 0.f;
#pragma unroll
    for (int i = 0; i < 16; ++i) m = fmaxf(m, yv[i]);
#pragma unroll
    for (int o = 32; o >= 1; o >>= 1) m = fmaxf(m, __shfl_xor(m, o, 64));
    if (lane == 0) smax[wv] = m;
    __syncthreads();
    const float rmax = fmaxf(fmaxf(smax[0], smax[1]), fmaxf(smax[2], smax[3]));
    const float adj = fmaxf(EPSV + THRESH - rmax, 0.f);
    unsigned km = 0;
    int cnt = 0;
#pragma unroll
    for (int i = 0; i < 16; ++i) {
      yv[i] += adj;
      bool keep = (yv[i] > THRESH) && !pad[base + s0 + i];
      if (keep) { km |= (1u << i); ++cnt; }
    }
    // wave inclusive scan of per-thread counts
    int inc = cnt;
#pragma unroll
    for (int o = 1; o < 64; o <<= 1) {
      int tmp = __shfl_up(inc, o, 64);
      if (lane >= o) inc += tmp;
    }
    if (lane == 63) ssum[wv] = inc;
    __syncthreads();
    int wpre = 0;
    for (int w = 0; w < wv; ++w) wpre += ssum[w];
    const int total = ssum[0] + ssum[1] + ssum[2] + ssum[3];
    int off = wpre + inc - cnt;   // exclusive offset, stable order
#pragma unroll
    for (int i = 0; i < 16; ++i) {
      int sdx = s0 + i;
      if ((km >> i) & 1u) {
        src_of_dest[base + off] = sdx;
        gval[base + off] = yv[i];
        ++off;
      }
      vpad[base + sdx] = (sdx >= total) ? 1.f : 0.f;
    }
    if (tid == 0) new_len[brow] = total;
  }
}

// ---------------------------------------------------------------------------
// K3: 16 output slots per block (2048 blocks): v = x[src]*gval or zeros.
// Nontemporal stores (native ext_vector float4) -- v is written once.
// (identical to R5/R9)
// ---------------------------------------------------------------------------
__global__ __launch_bounds__(256)
void k3_gather(const float* __restrict__ x, const float* __restrict__ gval,
               const int* __restrict__ src_of_dest, const int* __restrict__ new_len,
               float* __restrict__ v) {
  const int slot0 = blockIdx.x * 16;
  const int b = slot0 >> 12;            // 16 | 4096 -> same row for all 16
  const int nl = new_len[b];
  const int tid = threadIdx.x;
#pragma unroll
  for (int i = 0; i < 16; ++i) {
    const int slot = slot0 + i;
    const int dest = slot & (NS - 1);
    floatv4* vo = (floatv4*)(v + (size_t)slot * ND);
    floatv4 r;
    if (dest < nl) {
      const int src = src_of_dest[slot];
      const float g = gval[slot];
      floatv4 xv = ((const floatv4*)(x + ((size_t)b * NS + src) * ND))[tid];
      r = xv * g;
    } else {
      r = (floatv4)(0.f);
    }
    __builtin_nontemporal_store(r, vo + tid);
  }
}

extern "C" void kernel_launch(void* const* d_in, const int* in_sizes, int n_in,
                              void* d_out, int out_size, void* d_ws, size_t ws_size,
                              hipStream_t stream) {
  const float* x   = (const float*)d_in[0];
  const int*   pad = (const int*)d_in[1];
  const float* W1  = (const float*)d_in[2];
  const float* b1  = (const float*)d_in[3];
  const float* W2  = (const float*)d_in[4];
  const float* b2  = (const float*)d_in[5];

  float* v    = (float*)d_out;                 // [8,4096,1024]
  float* vpad = v + (size_t)NTOK * ND;         // [8,4096]

  // Wf scratch inside d_out's v region: k1 reads it, k3 later overwrites all
  // of v (same-stream ordering makes this safe, incl. rocprof replay).
  unsigned short* Wf = (unsigned short*)(v + 24000000);  // 2 MB packed W

  // d_ws (~384 KB): ysq, gval, src map, new_len, done_cnt
  float* ysq  = (float*)d_ws;                  // NTOK
  float* gval = ysq + NTOK;                    // NTOK
  int* src    = (int*)(gval + NTOK);           // NTOK
  int* nlen   = src + NTOK;                    // NB
  int* dcnt   = nlen + NB;                     // NB

  k0_prep<<<64, 256, 0, stream>>>(W1, Wf, dcnt);
  k1_gemm<<<NTOK / 64, 256, 0, stream>>>(x, Wf, b1, W2, pad, b2,
                                         ysq, dcnt, gval, src, nlen, vpad);
  k3_gather<<<NTOK / 16, 256, 0, stream>>>(x, gval, src, nlen, v);
}

// Round 7
// 320.847 us; speedup vs baseline: 1.1761x; 1.1761x over previous
//
#include <hip/hip_runtime.h>
#include <math.h>

// SoftGate: gate-MLP (split-bf16 MFMA, pipelined) -> threshold -> compaction.
// R12: k1 N-split BM64xBN256 (grid 1024, 4 blocks/CU) for cross-block drift.
#define NB 8
#define NS 4096
#define ND 1024      // K (feature dim)
#define NDH 512      // N (hidden dim)
#define NTOK (NB*NS) // M = 32768
#define THRESH 0.1f
#define EPSV 1e-5f

using short8   = __attribute__((ext_vector_type(8)))  short;
using floatx16 = __attribute__((ext_vector_type(16))) float;
using floatv4  = __attribute__((ext_vector_type(4)))  float;  // native vec for nontemporal

__device__ __forceinline__ unsigned short f32_to_bf16_rne(float f) {
  union { float f; unsigned u; } v; v.f = f;
  unsigned r = v.u + 0x7fffu + ((v.u >> 16) & 1u);
  return (unsigned short)(r >> 16);
}
__device__ __forceinline__ float bf16_to_f32(unsigned short h) {
  union { unsigned u; float f; } v; v.u = ((unsigned)h) << 16;
  return v.f;
}

// ---------------------------------------------------------------------------
// K0: repack W1 into MFMA-B-fragment order, bf16 hi/lo by 1 KB chunk:
//   chunk(n32,k16): lane l holds n=n32*32+(l&31), k=k16*16+(l>>5)*8+j.
// Also zeroes ysq (k1 accumulates into it with atomicAdd).
// ---------------------------------------------------------------------------
__global__ __launch_bounds__(256)
void k0_prep(const float* __restrict__ W1, unsigned short* __restrict__ Wf,
             float* __restrict__ ysq) {
  __shared__ float sw[16][513];
  const int t = threadIdx.x;
  const int k16 = blockIdx.x;                // 0..63
  // zero this block's 512-token slice of ysq (2 floats/thread)
  ysq[k16 * 512 + t] = 0.f;
  ysq[k16 * 512 + 256 + t] = 0.f;
#pragma unroll
  for (int i = 0; i < 8; ++i) {
    int flat = i * 256 + t;
    int r = flat >> 7, c4 = (flat & 127) << 2;
    *(float4*)&sw[r][c4] = *(const float4*)(W1 + (size_t)(k16 * 16 + r) * NDH + c4);
  }
  __syncthreads();
#pragma unroll
  for (int q = 0; q < 4; ++q) {
    int ss = q * 256 + t;
    int n32 = ss >> 6, lane = ss & 63;
    int n = n32 * 32 + (lane & 31);
    int kb = (lane >> 5) * 8;
    unsigned hi2[4], lo2[4];
#pragma unroll
    for (int j = 0; j < 4; ++j) {
      float w0 = sw[kb + 2 * j][n], w1 = sw[kb + 2 * j + 1][n];
      unsigned short h0 = f32_to_bf16_rne(w0), h1 = f32_to_bf16_rne(w1);
      unsigned short l0 = f32_to_bf16_rne(w0 - bf16_to_f32(h0));
      unsigned short l1 = f32_to_bf16_rne(w1 - bf16_to_f32(h1));
      hi2[j] = (unsigned)h0 | ((unsigned)h1 << 16);
      lo2[j] = (unsigned)l0 | ((unsigned)l1 << 16);
    }
    size_t cb = ((size_t)(n32 * 64 + k16) * 2) * 512 + (size_t)lane * 8;
    *(uint4*)(Wf + cb)       = make_uint4(hi2[0], hi2[1], hi2[2], hi2[3]);
    *(uint4*)(Wf + cb + 512) = make_uint4(lo2[0], lo2[1], lo2[2], lo2[3]);
  }
}

// ---------------------------------------------------------------------------
// K1: fused gate MLP. 3-term split-bf16 MFMA (hi·hi + lo·hi + hi·lo), fp32 acc.
// R12: R9 GEMM core with N-split: block = 64 tokens x 256 cols (bid>>1 = m
// tile, bid&1 = N half). Per-wave mt2 x nt2: 48 MFMA : 8 B-loads per iter --
// SAME compute:load ratio as R9 (R7's failure mode avoided); total B traffic
// unchanged (1 GB). acc halves to 64 VGPR -> (256,4) cap 128 with real slack
// -> 4 blocks/CU, each SIMD hosts 4 waves from 4 INDEPENDENT barrier domains;
// one block's convert/barrier/B-latency tail hides under another's MFMAs.
// Tail: per-token partial sum over the block's 256 cols, atomicAdd into ysq
// (exactly 2 adds/token, fp32 add commutative -> deterministic result).
// Squash/pad/rowmax moved to k2b. Numerics: same RNE converts, same per-acc
// term order; N-sum association changes once (two halves) ~1e-7 -- harmless.
// Tripwire: VGPR_Count <= 128 with WRITE_SIZE ~1-2 MB (no spill).
// ---------------------------------------------------------------------------
__global__ __launch_bounds__(256, 4)
void k1_gemm(const float* __restrict__ x, const unsigned short* __restrict__ Wf,
             const float* __restrict__ b1, const float* __restrict__ W2,
             float* __restrict__ ysq) {
  __shared__ __align__(16) unsigned short sx[2][2][64 * 72];  // [buf][hi/lo][m*72+k]
  __shared__ float red[4][64];

  const int tid = threadIdx.x;
  const int wave = tid >> 6, lane = tid & 63;
  const int l31 = lane & 31, h5 = lane >> 5;
  const int tok0 = (blockIdx.x >> 1) * 64;
  const int nhalf = blockIdx.x & 1;          // N half: cols [nhalf*256, +256)

  floatx16 acc[2][2];
#pragma unroll
  for (int mt = 0; mt < 2; ++mt)
#pragma unroll
    for (int nt = 0; nt < 2; ++nt)
#pragma unroll
      for (int r = 0; r < 16; ++r) acc[mt][nt][r] = 0.f;

  const int sm = tid >> 2;            // staging row 0..63 (4 threads/row)
  const int sk = (tid & 3) * 16;      // staging k-offset {0,16,32,48}
  const float* xrow = x + (size_t)(tok0 + sm) * ND + sk;

  const unsigned short* wb[2];
#pragma unroll
  for (int nt = 0; nt < 2; ++nt) {
    const int n32 = nhalf * 8 + wave * 2 + nt;   // 32-col chunk index
    wb[nt] = Wf + (((size_t)n32 * 64) * 2) * 512 + (size_t)lane * 8;
  }

  // convert+store 16 staged floats (4x float4) into LDS buffer bf
  auto stage_cvt = [&](int bf, const float4& a0, const float4& a1,
                       const float4& a2, const float4& a3) {
    float v16[16] = {a0.x, a0.y, a0.z, a0.w, a1.x, a1.y, a1.z, a1.w,
                     a2.x, a2.y, a2.z, a2.w, a3.x, a3.y, a3.z, a3.w};
    unsigned hp[8], lp[8];
#pragma unroll
    for (int j = 0; j < 8; ++j) {
      unsigned short h0 = f32_to_bf16_rne(v16[2 * j]);
      unsigned short h1 = f32_to_bf16_rne(v16[2 * j + 1]);
      unsigned short l0 = f32_to_bf16_rne(v16[2 * j] - bf16_to_f32(h0));
      unsigned short l1 = f32_to_bf16_rne(v16[2 * j + 1] - bf16_to_f32(h1));
      hp[j] = (unsigned)h0 | ((unsigned)h1 << 16);
      lp[j] = (unsigned)l0 | ((unsigned)l1 << 16);
    }
    *(uint4*)&sx[bf][0][sm * 72 + sk]     = make_uint4(hp[0], hp[1], hp[2], hp[3]);
    *(uint4*)&sx[bf][0][sm * 72 + sk + 8] = make_uint4(hp[4], hp[5], hp[6], hp[7]);
    *(uint4*)&sx[bf][1][sm * 72 + sk]     = make_uint4(lp[0], lp[1], lp[2], lp[3]);
    *(uint4*)&sx[bf][1][sm * 72 + sk + 8] = make_uint4(lp[4], lp[5], lp[6], lp[7]);
  };

  // prologue: stage x for it=0 into LDS buf 0
  {
    float4 a0 = *(const float4*)xrow;
    float4 a1 = *(const float4*)(xrow + 4);
    float4 a2 = *(const float4*)(xrow + 8);
    float4 a3 = *(const float4*)(xrow + 12);
    stage_cvt(0, a0, a1, a2, a3);
  }

  for (int it = 0; it < 16; ++it) {
    const int p = it & 1;
    __syncthreads();                  // LDS[p] ready; prev-iter prefetch drained
    // x prefetch for NEXT iter: issued first, consumed after the MFMA phase
    float4 pa0, pa1, pa2, pa3;
    if (it < 15) {
      const float* xp = xrow + (it + 1) * 64;
      pa0 = *(const float4*)xp;
      pa1 = *(const float4*)(xp + 4);
      pa2 = *(const float4*)(xp + 8);
      pa3 = *(const float4*)(xp + 12);
    }
    // 4 k16-subphases per barrier phase; B frags loaded per-k16 (progressive
    // vmcnt: k16+1's loads issue during k16's MFMAs).
#pragma unroll
    for (int kh = 0; kh < 4; ++kh) {
      short8 bh[2], bl[2];
#pragma unroll
      for (int nt = 0; nt < 2; ++nt) {
        const unsigned short* q = wb[nt] + ((size_t)(4 * it + kh) * 2) * 512;
        bh[nt] = *(const short8*)(q);
        bl[nt] = *(const short8*)(q + 512);
      }
      // A fragments: lane holds x[tok=mt*32+l31][k = kh*16 + h5*8 + j]
      short8 ah[2], al[2];
#pragma unroll
      for (int mt = 0; mt < 2; ++mt) {
        ah[mt] = *(const short8*)&sx[p][0][(mt * 32 + l31) * 72 + kh * 16 + h5 * 8];
        al[mt] = *(const short8*)&sx[p][1][(mt * 32 + l31) * 72 + kh * 16 + h5 * 8];
      }
      // term-outer MFMA issue: 4 independent accs between same-acc reuse;
      // per-acc order per k16 (hh,lh,hl) identical to R5/R9.
#pragma unroll
      for (int nt = 0; nt < 2; ++nt)
#pragma unroll
        for (int mt = 0; mt < 2; ++mt)
          acc[mt][nt] = __builtin_amdgcn_mfma_f32_32x32x16_bf16(ah[mt], bh[nt], acc[mt][nt], 0, 0, 0);
#pragma unroll
      for (int nt = 0; nt < 2; ++nt)
#pragma unroll
        for (int mt = 0; mt < 2; ++mt)
          acc[mt][nt] = __builtin_amdgcn_mfma_f32_32x32x16_bf16(al[mt], bh[nt], acc[mt][nt], 0, 0, 0);
#pragma unroll
      for (int nt = 0; nt < 2; ++nt)
#pragma unroll
        for (int mt = 0; mt < 2; ++mt)
          acc[mt][nt] = __builtin_amdgcn_mfma_f32_32x32x16_bf16(ah[mt], bl[nt], acc[mt][nt], 0, 0, 0);
    }
    // convert prefetched x -> other LDS buffer (ready for next barrier)
    if (it < 15) stage_cvt(p ^ 1, pa0, pa1, pa2, pa3);
  }

  // epilogue: relu(h+b1)*W2 over this block's 256 cols, shfl-reduce, LDS
  // combine, atomicAdd partial into ysq.
  // C/D layout (m74/m101): col=lane&31, row=(r&3)+8*(r>>2)+4*(lane>>5)
  float b1v[2], w2v[2];
#pragma unroll
  for (int nt = 0; nt < 2; ++nt) {
    const int n = nhalf * 256 + wave * 64 + nt * 32 + l31;
    b1v[nt] = b1[n];
    w2v[nt] = W2[n];
  }
#pragma unroll
  for (int mt = 0; mt < 2; ++mt) {
    float pr[16];
#pragma unroll
    for (int r = 0; r < 16; ++r) pr[r] = 0.f;
#pragma unroll
    for (int nt = 0; nt < 2; ++nt)
#pragma unroll
      for (int r = 0; r < 16; ++r)
        pr[r] += fmaxf(acc[mt][nt][r] + b1v[nt], 0.f) * w2v[nt];
#pragma unroll
    for (int m = 1; m <= 16; m <<= 1)
#pragma unroll
      for (int r = 0; r < 16; ++r) pr[r] += __shfl_xor(pr[r], m, 64);
    if (l31 == 0) {
#pragma unroll
      for (int r = 0; r < 16; ++r) {
        int row = (r & 3) + 8 * (r >> 2) + 4 * h5;
        red[wave][mt * 32 + row] = pr[r];
      }
    }
  }
  __syncthreads();
  if (tid < 64) {
    float s = red[0][tid] + red[1][tid] + red[2][tid] + red[3][tid];
    atomicAdd(ysq + tok0 + tid, s);   // 2 adds/token total; fp add commutes
  }
}

// ---------------------------------------------------------------------------
// K2b: per row -- squash(tanh)+pad-zero (moved from k1 tail), exact row max,
// adjust, threshold, stable shfl-scan compaction map, new_len, v_pad, gval.
// 1024 threads, 4 tokens/thread (R9's k2b scan structure).
// ---------------------------------------------------------------------------
__global__ __launch_bounds__(1024)
void k2b(const float* __restrict__ ysq, const int* __restrict__ pad,
         const float* __restrict__ b2, float* __restrict__ gval,
         int* __restrict__ src_of_dest, int* __restrict__ new_len,
         float* __restrict__ vpad_out) {
  __shared__ int ssum[16];
  __shared__ float ssmax[16];
  const int b = blockIdx.x, tid = threadIdx.x;
  const int lane = tid & 63, wv = tid >> 6;
  const int base = b * NS, s0 = tid * 4;
  const float b2v = b2[0];

  float4 yq = *(const float4*)(ysq + base + s0);
  int4 pq = *(const int4*)(pad + base + s0);
  float yv[4] = {yq.x, yq.y, yq.z, yq.w};
  int pv[4] = {pq.x, pq.y, pq.z, pq.w};
  float m4 = 0.f;
#pragma unroll
  for (int i = 0; i < 4; ++i) {
    float y = (1.f + tanhf(10.f * (yv[i] + b2v))) * 0.5f;
    if (pv[i]) y = 0.f;
    yv[i] = y;
    m4 = fmaxf(m4, y);
  }
  // exact row max: wave reduce -> LDS -> all threads
#pragma unroll
  for (int o = 32; o >= 1; o >>= 1) m4 = fmaxf(m4, __shfl_xor(m4, o, 64));
  if (lane == 0) ssmax[wv] = m4;
  __syncthreads();
  float rmax = ssmax[0];
#pragma unroll
  for (int w = 1; w < 16; ++w) rmax = fmaxf(rmax, ssmax[w]);
  const float adj = fmaxf(EPSV + THRESH - rmax, 0.f);

  unsigned km = 0;
  int cnt = 0;
#pragma unroll
  for (int i = 0; i < 4; ++i) {
    yv[i] += adj;
    bool keep = (yv[i] > THRESH) && !pv[i];
    if (keep) { km |= (1u << i); ++cnt; }
  }
  // wave inclusive scan of per-thread counts
  int inc = cnt;
#pragma unroll
  for (int o = 1; o < 64; o <<= 1) {
    int tmp = __shfl_up(inc, o, 64);
    if (lane >= o) inc += tmp;
  }
  if (lane == 63) ssum[wv] = inc;
  __syncthreads();
  int wpre = 0;
  int total = 0;
#pragma unroll
  for (int w = 0; w < 16; ++w) {
    int sv = ssum[w];
    if (w < wv) wpre += sv;
    total += sv;
  }
  int off = wpre + inc - cnt;   // exclusive offset, stable order
#pragma unroll
  for (int i = 0; i < 4; ++i) {
    int s = s0 + i;
    if ((km >> i) & 1u) {
      src_of_dest[base + off] = s;
      gval[base + off] = yv[i];
      ++off;
    }
    vpad_out[base + s] = (s >= total) ? 1.f : 0.f;
  }
  if (tid == 0) new_len[b] = total;
}

// ---------------------------------------------------------------------------
// K3: 16 output slots per block (2048 blocks): v = x[src]*gval or zeros.
// Nontemporal stores (native ext_vector float4) -- v is written once.
// (identical to R5/R9)
// ---------------------------------------------------------------------------
__global__ __launch_bounds__(256)
void k3_gather(const float* __restrict__ x, const float* __restrict__ gval,
               const int* __restrict__ src_of_dest, const int* __restrict__ new_len,
               float* __restrict__ v) {
  const int slot0 = blockIdx.x * 16;
  const int b = slot0 >> 12;            // 16 | 4096 -> same row for all 16
  const int nl = new_len[b];
  const int tid = threadIdx.x;
#pragma unroll
  for (int i = 0; i < 16; ++i) {
    const int slot = slot0 + i;
    const int dest = slot & (NS - 1);
    floatv4* vo = (floatv4*)(v + (size_t)slot * ND);
    floatv4 r;
    if (dest < nl) {
      const int src = src_of_dest[slot];
      const float g = gval[slot];
      floatv4 xv = ((const floatv4*)(x + ((size_t)b * NS + src) * ND))[tid];
      r = xv * g;
    } else {
      r = (floatv4)(0.f);
    }
    __builtin_nontemporal_store(r, vo + tid);
  }
}

extern "C" void kernel_launch(void* const* d_in, const int* in_sizes, int n_in,
                              void* d_out, int out_size, void* d_ws, size_t ws_size,
                              hipStream_t stream) {
  const float* x   = (const float*)d_in[0];
  const int*   pad = (const int*)d_in[1];
  const float* W1  = (const float*)d_in[2];
  const float* b1  = (const float*)d_in[3];
  const float* W2  = (const float*)d_in[4];
  const float* b2  = (const float*)d_in[5];

  float* v    = (float*)d_out;                 // [8,4096,1024]
  float* vpad = v + (size_t)NTOK * ND;         // [8,4096]

  // Wf scratch inside d_out's v region: k1 reads it, k3 later overwrites all
  // of v (same-stream ordering makes this safe, incl. rocprof replay).
  unsigned short* Wf = (unsigned short*)(v + 24000000);  // 2 MB packed W

  // d_ws (~384 KB): ysq, gval, src map, new_len
  float* ysq  = (float*)d_ws;                  // NTOK (pre-squash sums)
  float* gval = ysq + NTOK;                    // NTOK
  int* src    = (int*)(gval + NTOK);           // NTOK
  int* nlen   = src + NTOK;                    // NB

  k0_prep<<<64, 256, 0, stream>>>(W1, Wf, ysq);
  k1_gemm<<<NTOK / 32, 256, 0, stream>>>(x, Wf, b1, W2, ysq);  // 1024 blocks
  k2b<<<NB, 1024, 0, stream>>>(ysq, pad, b2, gval, src, nlen, vpad);
  k3_gather<<<NTOK / 16, 256, 0, stream>>>(x, gval, src, nlen, v);
}